// Round 1
// baseline (136.493 us; speedup 1.0000x reference)
//
#include <hip/hip_runtime.h>
#include <hip/hip_bf16.h>

// Shapes (fixed by the reference)
#define NB 8
#define NS 1024
#define ND 512
#define NH 8
#define NDK 64

typedef __attribute__((ext_vector_type(8))) short bf16x8;
typedef __attribute__((ext_vector_type(4))) short s16x4;
typedef __attribute__((ext_vector_type(4))) float f32x4;

__device__ __forceinline__ unsigned short bfround(float f) {
    union { float f; unsigned u; } v; v.f = f;
    unsigned u = v.u;
    u += 0x7fffu + ((u >> 16) & 1u);
    return (unsigned short)(u >> 16);
}

// ---------------------------------------------------------------------------
// Kernel 1: transpose + convert the four 512x512 fp32 weights (stored [in][out])
// into bf16 Wt[out][in] so the GEMM B-operand (k-contiguous per lane) reads
// linearly from LDS rows.
// ---------------------------------------------------------------------------
__global__ __launch_bounds__(256) void wt_kernel(const float* __restrict__ W0,
                                                 const float* __restrict__ W1,
                                                 const float* __restrict__ W2,
                                                 const float* __restrict__ W3,
                                                 unsigned short* __restrict__ wt) {
    __shared__ float sh[64][65];
    const int z = blockIdx.z;
    const float* W = z == 0 ? W0 : z == 1 ? W1 : z == 2 ? W2 : W3;
    unsigned short* out = wt + (size_t)z * ND * ND;
    const int o0 = blockIdx.x * 64, i0 = blockIdx.y * 64;
    const int tx = threadIdx.x & 63;
    const int ty = threadIdx.x >> 6;  // 0..3
    #pragma unroll
    for (int rr = 0; rr < 16; ++rr) {
        const int row = ty * 16 + rr;  // local i
        sh[row][tx] = W[(size_t)(i0 + row) * ND + o0 + tx];
    }
    __syncthreads();
    #pragma unroll
    for (int rr = 0; rr < 16; ++rr) {
        const int row = ty * 16 + rr;  // local o
        out[(size_t)(o0 + row) * ND + i0 + tx] = bfround(sh[tx][row]);
    }
}

// ---------------------------------------------------------------------------
// Kernel 2/5: GEMM  out = A(8192x512) @ W(512x512) + bias
// A_F32:  A is fp32 (raw input), converted to bf16 during LDS staging.
// OUT_F32: write fp32 flat [M][N] (final projection to d_out);
//          else write bf16 into (B,H,S,DK) layout.
// Block: 256 thr (4 waves), tile 128x128, BK=32, wave tile 64x64 (4x4 frags).
// ---------------------------------------------------------------------------
template <bool A_F32, bool OUT_F32>
__global__ __launch_bounds__(256) void gemm_kernel(
    const void* __restrict__ A0, const void* __restrict__ A1, const void* __restrict__ A2,
    const unsigned short* __restrict__ wt_base, int wt_stride,
    const float* __restrict__ b0, const float* __restrict__ b1, const float* __restrict__ b2,
    void* __restrict__ out_base, size_t out_stride_bytes) {
    __shared__ unsigned short As[128][40];  // +8 pad: 2-way banks (free)
    __shared__ unsigned short Bs[128][40];
    const int t = threadIdx.x;
    const int lane = t & 63, w = t >> 6;
    const int wr = w >> 1, wc = w & 1;
    const int lr = lane & 15, lg = lane >> 4;
    const int z = blockIdx.z;
    const void* Ap = z == 0 ? A0 : z == 1 ? A1 : A2;
    const float* bias = z == 0 ? b0 : z == 1 ? b1 : b2;
    const unsigned short* Wt = wt_base + (size_t)z * wt_stride;
    void* outp = (void*)((char*)out_base + (size_t)z * out_stride_bytes);
    const int m0 = blockIdx.y * 128, n0 = blockIdx.x * 128;

    f32x4 acc[4][4];
    #pragma unroll
    for (int i = 0; i < 4; ++i)
        #pragma unroll
        for (int j = 0; j < 4; ++j) acc[i][j] = (f32x4){0.f, 0.f, 0.f, 0.f};

    for (int kt = 0; kt < 16; ++kt) {
        const int k0 = kt * 32;
        __syncthreads();
        if (A_F32) {
            const float* A = (const float*)Ap;
            const int mrow = t >> 3, k4 = (t & 7) * 4;
            #pragma unroll
            for (int r = 0; r < 4; ++r) {
                const int m = mrow + 32 * r;
                float4 v = *(const float4*)(A + (size_t)(m0 + m) * ND + k0 + k4);
                s16x4 p = {(short)bfround(v.x), (short)bfround(v.y),
                           (short)bfround(v.z), (short)bfround(v.w)};
                *(s16x4*)(&As[m][k4]) = p;
            }
        } else {
            const unsigned short* A = (const unsigned short*)Ap;
            #pragma unroll
            for (int r = 0; r < 2; ++r) {
                const int idx = t + 256 * r;
                const int m = idx >> 2, k8 = (idx & 3) * 8;
                *(bf16x8*)(&As[m][k8]) =
                    *(const bf16x8*)(A + (size_t)(m0 + m) * ND + k0 + k8);
            }
        }
        #pragma unroll
        for (int r = 0; r < 2; ++r) {
            const int idx = t + 256 * r;
            const int n = idx >> 2, k8 = (idx & 3) * 8;
            *(bf16x8*)(&Bs[n][k8]) =
                *(const bf16x8*)(Wt + (size_t)(n0 + n) * ND + k0 + k8);
        }
        __syncthreads();
        bf16x8 af[4], bfv[4];
        #pragma unroll
        for (int mi = 0; mi < 4; ++mi)
            af[mi] = *(const bf16x8*)(&As[wr * 64 + mi * 16 + lr][lg * 8]);
        #pragma unroll
        for (int nj = 0; nj < 4; ++nj)
            bfv[nj] = *(const bf16x8*)(&Bs[wc * 64 + nj * 16 + lr][lg * 8]);
        #pragma unroll
        for (int mi = 0; mi < 4; ++mi)
            #pragma unroll
            for (int nj = 0; nj < 4; ++nj)
                acc[mi][nj] = __builtin_amdgcn_mfma_f32_16x16x32_bf16(
                    af[mi], bfv[nj], acc[mi][nj], 0, 0, 0);
    }

    #pragma unroll
    for (int mi = 0; mi < 4; ++mi) {
        #pragma unroll
        for (int nj = 0; nj < 4; ++nj) {
            const int n = n0 + wc * 64 + nj * 16 + lr;
            const float bv = bias[n];
            #pragma unroll
            for (int r = 0; r < 4; ++r) {
                const int m = m0 + wr * 64 + mi * 16 + lg * 4 + r;
                const float val = acc[mi][nj][r] + bv;
                if (OUT_F32) {
                    ((float*)outp)[(size_t)m * ND + n] = val;
                } else {
                    const int bb = m >> 10, s = m & 1023;    // m = b*S + s
                    const int hh = n >> 6, dk = n & 63;      // n = h*64 + dk
                    ((unsigned short*)outp)[(((size_t)(bb * NH + hh) * NS + s) << 6) + dk] =
                        bfround(val);
                }
            }
        }
    }
}

// ---------------------------------------------------------------------------
// Kernel 3: per-(b,h) transpose V (S,DK) -> Vt (DK,S) so PV's B-operand
// (k=kv contiguous per lane) reads linearly.
// ---------------------------------------------------------------------------
__global__ __launch_bounds__(256) void vt_kernel(const unsigned short* __restrict__ Vb,
                                                 unsigned short* __restrict__ Vt) {
    __shared__ unsigned short Ts[64][72];
    const int t = threadIdx.x;
    const int bh = blockIdx.y;
    const int s0 = blockIdx.x * 64;
    const unsigned short* Vh = Vb + (size_t)bh * NS * NDK;
    unsigned short* Vth = Vt + (size_t)bh * NDK * NS;
    #pragma unroll
    for (int r = 0; r < 2; ++r) {
        const int idx = t + 256 * r;
        const int sl = idx >> 3, d8 = (idx & 7) * 8;
        *(bf16x8*)(&Ts[sl][d8]) = *(const bf16x8*)(Vh + (size_t)(s0 + sl) * NDK + d8);
    }
    __syncthreads();
    #pragma unroll
    for (int r = 0; r < 2; ++r) {
        const int idx = t + 256 * r;
        const int dl = idx >> 3, s8 = (idx & 7) * 8;
        unsigned short tmp[8];
        #pragma unroll
        for (int e = 0; e < 8; ++e) tmp[e] = Ts[s8 + e][dl];
        *(bf16x8*)(Vth + (size_t)dl * NS + s0 + s8) = *(bf16x8*)tmp;
    }
}

// ---------------------------------------------------------------------------
// Kernel 4: flash attention per (b,h). Block = 128 q rows (4 waves x 32),
// KV tiles of 64. Online softmax (fp32), P via LDS, output bf16 into
// X[b][s][h*64+dk] (ready for the output projection GEMM).
// ---------------------------------------------------------------------------
__global__ __launch_bounds__(256) void attn_kernel(const unsigned short* __restrict__ Qb,
                                                   const unsigned short* __restrict__ Kb,
                                                   const unsigned short* __restrict__ Vt,
                                                   const int* __restrict__ mask,
                                                   unsigned short* __restrict__ Xb) {
    __shared__ unsigned short Ks[64][72];   // [kv][dk], pad 8
    __shared__ unsigned short Vs[64][72];   // [dk][kv]
    __shared__ unsigned short Ps[128][72];  // [q][kv]
    const int t = threadIdx.x;
    const int lane = t & 63, w = t >> 6;
    const int lr = lane & 15, lg = lane >> 4;
    const int bh = blockIdx.y;
    const int b = bh >> 3, h = bh & 7;
    const int q0 = blockIdx.x * 128;
    const unsigned short* Qh = Qb + (size_t)bh * NS * NDK;
    const unsigned short* Kh = Kb + (size_t)bh * NS * NDK;
    const unsigned short* Vh = Vt + (size_t)bh * NDK * NS;
    const int* mk = mask + b * NS;

    // Q fragments live in registers for the whole kv loop.
    bf16x8 qf[2][2];
    #pragma unroll
    for (int mi = 0; mi < 2; ++mi)
        #pragma unroll
        for (int kk = 0; kk < 2; ++kk) {
            const int row = q0 + w * 32 + mi * 16 + lr;
            qf[mi][kk] = *(const bf16x8*)(Qh + (size_t)row * NDK + kk * 32 + lg * 8);
        }

    f32x4 xacc[2][4];
    #pragma unroll
    for (int i = 0; i < 2; ++i)
        #pragma unroll
        for (int j = 0; j < 4; ++j) xacc[i][j] = (f32x4){0.f, 0.f, 0.f, 0.f};
    float mst[2][4], lst[2][4];
    #pragma unroll
    for (int i = 0; i < 2; ++i)
        #pragma unroll
        for (int r = 0; r < 4; ++r) { mst[i][r] = -3.0e38f; lst[i][r] = 0.f; }

    for (int it = 0; it < 16; ++it) {
        const int kv0 = it * 64;
        __syncthreads();  // previous iter's LDS reads done before overwrite
        #pragma unroll
        for (int r = 0; r < 2; ++r) {  // stage K tile [kv][dk]
            const int idx = t + 256 * r;
            const int kv = idx >> 3, d8 = (idx & 7) * 8;
            *(bf16x8*)(&Ks[kv][d8]) =
                *(const bf16x8*)(Kh + (size_t)(kv0 + kv) * NDK + d8);
        }
        #pragma unroll
        for (int r = 0; r < 2; ++r) {  // stage V^T tile [dk][kv] (already transposed)
            const int idx = t + 256 * r;
            const int dl = idx >> 3, kv8 = (idx & 7) * 8;
            *(bf16x8*)(&Vs[dl][kv8]) =
                *(const bf16x8*)(Vh + (size_t)dl * NS + kv0 + kv8);
        }
        int mvals[4];
        #pragma unroll
        for (int nj = 0; nj < 4; ++nj) mvals[nj] = mk[kv0 + nj * 16 + lr];
        __syncthreads();

        // scores = Q K^T
        f32x4 sc[2][4];
        #pragma unroll
        for (int i = 0; i < 2; ++i)
            #pragma unroll
            for (int j = 0; j < 4; ++j) sc[i][j] = (f32x4){0.f, 0.f, 0.f, 0.f};
        bf16x8 kf[4][2];
        #pragma unroll
        for (int nj = 0; nj < 4; ++nj)
            #pragma unroll
            for (int kk = 0; kk < 2; ++kk)
                kf[nj][kk] = *(const bf16x8*)(&Ks[nj * 16 + lr][kk * 32 + lg * 8]);
        #pragma unroll
        for (int mi = 0; mi < 2; ++mi)
            #pragma unroll
            for (int nj = 0; nj < 4; ++nj)
                #pragma unroll
                for (int kk = 0; kk < 2; ++kk)
                    sc[mi][nj] = __builtin_amdgcn_mfma_f32_16x16x32_bf16(
                        qf[mi][kk], kf[nj][kk], sc[mi][nj], 0, 0, 0);

        // online softmax (scale 1/sqrt(64)=0.125); masked keys -> p=0
        #pragma unroll
        for (int mi = 0; mi < 2; ++mi) {
            #pragma unroll
            for (int nj = 0; nj < 4; ++nj)
                #pragma unroll
                for (int r = 0; r < 4; ++r)
                    sc[mi][nj][r] = mvals[nj] ? sc[mi][nj][r] * 0.125f : -3.0e38f;
            #pragma unroll
            for (int r = 0; r < 4; ++r) {
                float tm = fmaxf(fmaxf(sc[mi][0][r], sc[mi][1][r]),
                                 fmaxf(sc[mi][2][r], sc[mi][3][r]));
                tm = fmaxf(tm, __shfl_xor(tm, 1));
                tm = fmaxf(tm, __shfl_xor(tm, 2));
                tm = fmaxf(tm, __shfl_xor(tm, 4));
                tm = fmaxf(tm, __shfl_xor(tm, 8));
                const float mo = mst[mi][r];
                const float mn = fmaxf(mo, tm);
                const float f = __expf(mo - mn);  // mo=-3e38 -> f underflows to 0
                float rs = 0.f;
                #pragma unroll
                for (int nj = 0; nj < 4; ++nj) {
                    const float p = mvals[nj] ? __expf(sc[mi][nj][r] - mn) : 0.f;
                    sc[mi][nj][r] = p;
                    rs += p;
                }
                rs += __shfl_xor(rs, 1);
                rs += __shfl_xor(rs, 2);
                rs += __shfl_xor(rs, 4);
                rs += __shfl_xor(rs, 8);
                lst[mi][r] = lst[mi][r] * f + rs;
                mst[mi][r] = mn;
                #pragma unroll
                for (int nd = 0; nd < 4; ++nd) xacc[mi][nd][r] *= f;
            }
        }

        // P -> LDS (bf16), per-wave region; same-wave read below (lgkmcnt-ordered)
        #pragma unroll
        for (int mi = 0; mi < 2; ++mi)
            #pragma unroll
            for (int nj = 0; nj < 4; ++nj)
                #pragma unroll
                for (int r = 0; r < 4; ++r)
                    Ps[w * 32 + mi * 16 + lg * 4 + r][nj * 16 + lr] =
                        bfround(sc[mi][nj][r]);

        // X += P V
        bf16x8 vf[4][2], pf[2][2];
        #pragma unroll
        for (int nd = 0; nd < 4; ++nd)
            #pragma unroll
            for (int kk = 0; kk < 2; ++kk)
                vf[nd][kk] = *(const bf16x8*)(&Vs[nd * 16 + lr][kk * 32 + lg * 8]);
        #pragma unroll
        for (int mi = 0; mi < 2; ++mi)
            #pragma unroll
            for (int kk = 0; kk < 2; ++kk)
                pf[mi][kk] = *(const bf16x8*)(&Ps[w * 32 + mi * 16 + lr][kk * 32 + lg * 8]);
        #pragma unroll
        for (int mi = 0; mi < 2; ++mi)
            #pragma unroll
            for (int nd = 0; nd < 4; ++nd)
                #pragma unroll
                for (int kk = 0; kk < 2; ++kk)
                    xacc[mi][nd] = __builtin_amdgcn_mfma_f32_16x16x32_bf16(
                        pf[mi][kk], vf[nd][kk], xacc[mi][nd], 0, 0, 0);
    }

    // epilogue: X[b][s][h*64+dk] = xacc / l
    #pragma unroll
    for (int mi = 0; mi < 2; ++mi)
        #pragma unroll
        for (int r = 0; r < 4; ++r) {
            const float l = lst[mi][r];
            const float inv = l > 0.f ? 1.f / l : 0.f;
            const int q = q0 + w * 32 + mi * 16 + lg * 4 + r;
            #pragma unroll
            for (int nd = 0; nd < 4; ++nd)
                Xb[(size_t)(b * NS + q) * ND + h * 64 + nd * 16 + lr] =
                    bfround(xacc[mi][nd][r] * inv);
        }
}

// ---------------------------------------------------------------------------
// Host launcher. Workspace layout (bf16 elements):
//   wt   : 4 * 512*512            (Wq^T, Wk^T, Wv^T, Wo^T)
//   Qb   : B*H*S*DK
//   Kb   : B*H*S*DK
//   Vb   : B*H*S*DK
//   Vt   : B*H*DK*S
//   Xb   : B*S*D
// total = 44 MB.
// ---------------------------------------------------------------------------
extern "C" void kernel_launch(void* const* d_in, const int* in_sizes, int n_in,
                              void* d_out, int out_size, void* d_ws, size_t ws_size,
                              hipStream_t stream) {
    const float* query = (const float*)d_in[0];
    const float* key   = (const float*)d_in[1];
    const float* value = (const float*)d_in[2];
    const int*   mask  = (const int*)d_in[3];
    const float* Wq = (const float*)d_in[4];
    const float* bq = (const float*)d_in[5];
    const float* Wk = (const float*)d_in[6];
    const float* bk = (const float*)d_in[7];
    const float* Wv = (const float*)d_in[8];
    const float* bv = (const float*)d_in[9];
    const float* Wo = (const float*)d_in[10];
    const float* bo = (const float*)d_in[11];

    const size_t HEADSZ = (size_t)NB * NH * NS * NDK;  // 4194304
    unsigned short* wt = (unsigned short*)d_ws;
    unsigned short* Qb = wt + (size_t)4 * ND * ND;
    unsigned short* Kb = Qb + HEADSZ;
    unsigned short* Vb = Kb + HEADSZ;
    unsigned short* Vt = Vb + HEADSZ;
    unsigned short* Xb = Vt + HEADSZ;

    // 1. weights -> bf16, transposed
    wt_kernel<<<dim3(8, 8, 4), 256, 0, stream>>>(Wq, Wk, Wv, Wo, wt);

    // 2. QKV projections (one launch, z = q/k/v)
    gemm_kernel<true, false><<<dim3(4, 64, 3), 256, 0, stream>>>(
        query, key, value, wt, ND * ND, bq, bk, bv, (void*)Qb, HEADSZ * 2);

    // 3. V -> V^T per head
    vt_kernel<<<dim3(16, NB * NH), 256, 0, stream>>>(Vb, Vt);

    // 4. attention
    attn_kernel<<<dim3(NS / 128, NB * NH), 256, 0, stream>>>(Qb, Kb, Vt, mask, Xb);

    // 5. output projection (fp32 out)
    gemm_kernel<false, true><<<dim3(4, 64, 1), 256, 0, stream>>>(
        Xb, Xb, Xb, wt + (size_t)3 * ND * ND, 0, bo, bo, bo, d_out, 0);
}

// Round 2
// 118.434 us; speedup vs baseline: 1.1525x; 1.1525x over previous
//
#include <hip/hip_runtime.h>
#include <hip/hip_bf16.h>

// Shapes (fixed by the reference)
#define NB 8
#define NS 1024
#define ND 512
#define NH 8
#define NDK 64

typedef __attribute__((ext_vector_type(8))) short bf16x8;
typedef __attribute__((ext_vector_type(4))) short s16x4;
typedef __attribute__((ext_vector_type(4))) float f32x4;

// scores are computed in exp2 domain: Q is pre-scaled by 0.125 * log2(e)
#define QSCALE 0.18033688011112042f
#define NEGBIG -3.0e38f

__device__ __forceinline__ unsigned short bfround(float f) {
    union { float f; unsigned u; } v; v.f = f;
    unsigned u = v.u;
    u += 0x7fffu + ((u >> 16) & 1u);
    return (unsigned short)(u >> 16);
}

// ---------------------------------------------------------------------------
// Kernel 1: transpose + convert the four 512x512 fp32 weights ([in][out]) into
// bf16 Wt[out][in] so the GEMM B-operand (k-contiguous per lane) reads linearly.
// ---------------------------------------------------------------------------
__global__ __launch_bounds__(256) void wt_kernel(const float* __restrict__ W0,
                                                 const float* __restrict__ W1,
                                                 const float* __restrict__ W2,
                                                 const float* __restrict__ W3,
                                                 unsigned short* __restrict__ wt) {
    __shared__ float sh[64][65];
    const int z = blockIdx.z;
    const float* W = z == 0 ? W0 : z == 1 ? W1 : z == 2 ? W2 : W3;
    unsigned short* out = wt + (size_t)z * ND * ND;
    const int o0 = blockIdx.x * 64, i0 = blockIdx.y * 64;
    const int tx = threadIdx.x & 63;
    const int ty = threadIdx.x >> 6;  // 0..3
    #pragma unroll
    for (int rr = 0; rr < 16; ++rr) {
        const int row = ty * 16 + rr;  // local i
        sh[row][tx] = W[(size_t)(i0 + row) * ND + o0 + tx];
    }
    __syncthreads();
    #pragma unroll
    for (int rr = 0; rr < 16; ++rr) {
        const int row = ty * 16 + rr;  // local o
        out[(size_t)(o0 + row) * ND + i0 + tx] = bfround(sh[tx][row]);
    }
}

// ---------------------------------------------------------------------------
// Kernel 2/5: GEMM  out = A(8192x512) @ W(512x512) + bias
// A_F32:  A is fp32 (raw input), converted to bf16 during LDS staging via
//         v_cvt_pk_bf16_f32 (RNE, 2 floats/instr).
// OUT_F32: write fp32 flat [M][N]; else bf16 into (B,H,S,DK), with z==0 (Q)
//          pre-scaled by QSCALE.
// 1-D grid with bijective XCD swizzle: blocks sharing an A panel (same m-tile,
// 4 n-tiles) get consecutive swizzled ids -> same XCD L2.
// ---------------------------------------------------------------------------
template <bool A_F32, bool OUT_F32>
__global__ __launch_bounds__(256) void gemm_kernel(
    const void* __restrict__ A0, const void* __restrict__ A1, const void* __restrict__ A2,
    const unsigned short* __restrict__ wt_base, int wt_stride,
    const float* __restrict__ b0, const float* __restrict__ b1, const float* __restrict__ b2,
    void* __restrict__ out_base, size_t out_stride_bytes) {
    __shared__ unsigned short As[128][40];
    __shared__ unsigned short Bs[128][40];
    const int t = threadIdx.x;
    const int lane = t & 63, w = t >> 6;
    const int wr = w >> 1, wc = w & 1;
    const int lr = lane & 15, lg = lane >> 4;
    // XCD swizzle (gridDim.x % 8 == 0 always here)
    const int bid = blockIdx.x;
    const int u = (bid & 7) * (gridDim.x >> 3) + (bid >> 3);
    const int xt = u & 3, yt = (u >> 2) & 63, z = u >> 8;
    const void* Ap = z == 0 ? A0 : z == 1 ? A1 : A2;
    const float* bias = z == 0 ? b0 : z == 1 ? b1 : b2;
    const unsigned short* Wt = wt_base + (size_t)z * wt_stride;
    void* outp = (void*)((char*)out_base + (size_t)z * out_stride_bytes);
    const int m0 = yt * 128, n0 = xt * 128;

    f32x4 acc[4][4];
    #pragma unroll
    for (int i = 0; i < 4; ++i)
        #pragma unroll
        for (int j = 0; j < 4; ++j) acc[i][j] = (f32x4){0.f, 0.f, 0.f, 0.f};

    for (int kt = 0; kt < 16; ++kt) {
        const int k0 = kt * 32;
        __syncthreads();
        if (A_F32) {
            const float* A = (const float*)Ap;
            const int mrow = t >> 3, k4 = (t & 7) * 4;
            #pragma unroll
            for (int r = 0; r < 4; ++r) {
                const int m = mrow + 32 * r;
                float4 v = *(const float4*)(A + (size_t)(m0 + m) * ND + k0 + k4);
                unsigned p0, p1;
                asm("v_cvt_pk_bf16_f32 %0, %1, %2" : "=v"(p0) : "v"(v.x), "v"(v.y));
                asm("v_cvt_pk_bf16_f32 %0, %1, %2" : "=v"(p1) : "v"(v.z), "v"(v.w));
                uint2 pv; pv.x = p0; pv.y = p1;
                *(uint2*)(&As[m][k4]) = pv;
            }
        } else {
            const unsigned short* A = (const unsigned short*)Ap;
            #pragma unroll
            for (int r = 0; r < 2; ++r) {
                const int idx = t + 256 * r;
                const int m = idx >> 2, k8 = (idx & 3) * 8;
                *(bf16x8*)(&As[m][k8]) =
                    *(const bf16x8*)(A + (size_t)(m0 + m) * ND + k0 + k8);
            }
        }
        #pragma unroll
        for (int r = 0; r < 2; ++r) {
            const int idx = t + 256 * r;
            const int n = idx >> 2, k8 = (idx & 3) * 8;
            *(bf16x8*)(&Bs[n][k8]) =
                *(const bf16x8*)(Wt + (size_t)(n0 + n) * ND + k0 + k8);
        }
        __syncthreads();
        bf16x8 af[4], bfv[4];
        #pragma unroll
        for (int mi = 0; mi < 4; ++mi)
            af[mi] = *(const bf16x8*)(&As[wr * 64 + mi * 16 + lr][lg * 8]);
        #pragma unroll
        for (int nj = 0; nj < 4; ++nj)
            bfv[nj] = *(const bf16x8*)(&Bs[wc * 64 + nj * 16 + lr][lg * 8]);
        #pragma unroll
        for (int mi = 0; mi < 4; ++mi)
            #pragma unroll
            for (int nj = 0; nj < 4; ++nj)
                acc[mi][nj] = __builtin_amdgcn_mfma_f32_16x16x32_bf16(
                    af[mi], bfv[nj], acc[mi][nj], 0, 0, 0);
    }

    const float osc = (!OUT_F32 && z == 0) ? QSCALE : 1.0f;
    #pragma unroll
    for (int mi = 0; mi < 4; ++mi) {
        #pragma unroll
        for (int nj = 0; nj < 4; ++nj) {
            const int n = n0 + wc * 64 + nj * 16 + lr;
            const float bv = bias[n];
            #pragma unroll
            for (int r = 0; r < 4; ++r) {
                const int m = m0 + wr * 64 + mi * 16 + lg * 4 + r;
                const float val = (acc[mi][nj][r] + bv) * osc;
                if (OUT_F32) {
                    ((float*)outp)[(size_t)m * ND + n] = val;
                } else {
                    const int bb = m >> 10, s = m & 1023;    // m = b*S + s
                    const int hh = n >> 6, dk = n & 63;      // n = h*64 + dk
                    ((unsigned short*)outp)[(((size_t)(bb * NH + hh) * NS + s) << 6) + dk] =
                        bfround(val);
                }
            }
        }
    }
}

// ---------------------------------------------------------------------------
// Kernel 3: per-(b,h) transpose V (S,DK) -> Vt (DK,S) so PV's B-operand
// (k=kv contiguous per lane) reads linearly.
// ---------------------------------------------------------------------------
__global__ __launch_bounds__(256) void vt_kernel(const unsigned short* __restrict__ Vb,
                                                 unsigned short* __restrict__ Vt) {
    __shared__ unsigned short Ts[64][72];
    const int t = threadIdx.x;
    const int bh = blockIdx.y;
    const int s0 = blockIdx.x * 64;
    const unsigned short* Vh = Vb + (size_t)bh * NS * NDK;
    unsigned short* Vth = Vt + (size_t)bh * NDK * NS;
    #pragma unroll
    for (int r = 0; r < 2; ++r) {
        const int idx = t + 256 * r;
        const int sl = idx >> 3, d8 = (idx & 7) * 8;
        *(bf16x8*)(&Ts[sl][d8]) = *(const bf16x8*)(Vh + (size_t)(s0 + sl) * NDK + d8);
    }
    __syncthreads();
    #pragma unroll
    for (int r = 0; r < 2; ++r) {
        const int idx = t + 256 * r;
        const int dl = idx >> 3, s8 = (idx & 7) * 8;
        unsigned short tmp[8];
        #pragma unroll
        for (int e = 0; e < 8; ++e) tmp[e] = Ts[s8 + e][dl];
        *(bf16x8*)(Vth + (size_t)dl * NS + s0 + s8) = *(bf16x8*)tmp;
    }
}

// ---------------------------------------------------------------------------
// Kernel 4: flash attention per (b,h). Block = 64 q rows (4 waves x 16),
// KV tiles of 64, grid 16*64=1024 (4 blocks/CU -> 16 waves/CU).
// Scores arrive pre-scaled in exp2 domain (Q carries 0.125*log2e).
// Mask is an additive bias (0 / -3e38): exp2 underflow zeroes masked probs.
// T13: rescale of xacc skipped via wave-uniform __any when max didn't grow.
// ---------------------------------------------------------------------------
__global__ __launch_bounds__(256, 4) void attn_kernel(const unsigned short* __restrict__ Qb,
                                                      const unsigned short* __restrict__ Kb,
                                                      const unsigned short* __restrict__ Vt,
                                                      const int* __restrict__ mask,
                                                      unsigned short* __restrict__ Xb) {
    __shared__ unsigned short Ks[64][72];  // [kv][dk]
    __shared__ unsigned short Vs[64][72];  // [dk][kv]
    __shared__ unsigned short Ps[64][72];  // [q][kv]
    const int t = threadIdx.x;
    const int lane = t & 63, w = t >> 6;
    const int lr = lane & 15, lg = lane >> 4;
    // XCD swizzle: 16 q-tiles of one head contiguous -> same XCD L2 for K/V
    const int bid = blockIdx.x;
    const int u = (bid & 7) * 128 + (bid >> 3);
    const int bh = u >> 4, xq = u & 15;
    const int b = bh >> 3, h = bh & 7;
    const int q0 = xq * 64;
    const unsigned short* Qh = Qb + (size_t)bh * NS * NDK;
    const unsigned short* Kh = Kb + (size_t)bh * NS * NDK;
    const unsigned short* Vh = Vt + (size_t)bh * NDK * NS;
    const int* mk = mask + b * NS;
    const int qrow = q0 + w * 16;

    bf16x8 qf[2];
    #pragma unroll
    for (int kk = 0; kk < 2; ++kk)
        qf[kk] = *(const bf16x8*)(Qh + (size_t)(qrow + lr) * NDK + kk * 32 + lg * 8);

    f32x4 xacc[4];
    #pragma unroll
    for (int j = 0; j < 4; ++j) xacc[j] = (f32x4){0.f, 0.f, 0.f, 0.f};
    float mst[4], lst[4];
    #pragma unroll
    for (int r = 0; r < 4; ++r) { mst[r] = -1.0e30f; lst[r] = 0.f; }

    for (int it = 0; it < 16; ++it) {
        const int kv0 = it * 64;
        __syncthreads();
        {   // stage K tile [kv][dk] and V^T tile [dk][kv]; 256 thr x 2 chunks each
            const int kv = t >> 3, d8 = (t & 7) * 8;
            *(bf16x8*)(&Ks[kv][d8]) = *(const bf16x8*)(Kh + (size_t)(kv0 + kv) * NDK + d8);
            const int kv2 = (t + 256) >> 3, d82 = ((t + 256) & 7) * 8;
            *(bf16x8*)(&Ks[kv2][d82]) = *(const bf16x8*)(Kh + (size_t)(kv0 + kv2) * NDK + d82);
            *(bf16x8*)(&Vs[kv][d8]) = *(const bf16x8*)(Vh + (size_t)kv * NS + kv0 + d8);
            *(bf16x8*)(&Vs[kv2][d82]) = *(const bf16x8*)(Vh + (size_t)kv2 * NS + kv0 + d82);
        }
        float bias[4];
        #pragma unroll
        for (int nj = 0; nj < 4; ++nj)
            bias[nj] = mk[kv0 + nj * 16 + lr] ? 0.f : NEGBIG;
        __syncthreads();

        // scores (exp2 domain already)
        f32x4 sc[4];
        #pragma unroll
        for (int nj = 0; nj < 4; ++nj) {
            sc[nj] = (f32x4){0.f, 0.f, 0.f, 0.f};
            bf16x8 k0f = *(const bf16x8*)(&Ks[nj * 16 + lr][lg * 8]);
            bf16x8 k1f = *(const bf16x8*)(&Ks[nj * 16 + lr][32 + lg * 8]);
            sc[nj] = __builtin_amdgcn_mfma_f32_16x16x32_bf16(qf[0], k0f, sc[nj], 0, 0, 0);
            sc[nj] = __builtin_amdgcn_mfma_f32_16x16x32_bf16(qf[1], k1f, sc[nj], 0, 0, 0);
        }
        #pragma unroll
        for (int nj = 0; nj < 4; ++nj)
            #pragma unroll
            for (int r = 0; r < 4; ++r) sc[nj][r] += bias[nj];

        // online softmax over kv (rows r; kv spread over nj x lr)
        float mn[4], rs[4];
        bool ch = false;
        #pragma unroll
        for (int r = 0; r < 4; ++r) {
            float tm = fmaxf(fmaxf(sc[0][r], sc[1][r]), fmaxf(sc[2][r], sc[3][r]));
            tm = fmaxf(tm, __shfl_xor(tm, 1));
            tm = fmaxf(tm, __shfl_xor(tm, 2));
            tm = fmaxf(tm, __shfl_xor(tm, 4));
            tm = fmaxf(tm, __shfl_xor(tm, 8));
            mn[r] = fmaxf(mst[r], tm);
            ch = ch || (mn[r] > mst[r]);
            float s0 = __builtin_amdgcn_exp2f(sc[0][r] - mn[r]);
            float s1 = __builtin_amdgcn_exp2f(sc[1][r] - mn[r]);
            float s2 = __builtin_amdgcn_exp2f(sc[2][r] - mn[r]);
            float s3 = __builtin_amdgcn_exp2f(sc[3][r] - mn[r]);
            sc[0][r] = s0; sc[1][r] = s1; sc[2][r] = s2; sc[3][r] = s3;
            float sum = (s0 + s1) + (s2 + s3);
            sum += __shfl_xor(sum, 1);
            sum += __shfl_xor(sum, 2);
            sum += __shfl_xor(sum, 4);
            sum += __shfl_xor(sum, 8);
            rs[r] = sum;
        }
        if (__any(ch)) {
            #pragma unroll
            for (int r = 0; r < 4; ++r) {
                const float f = __builtin_amdgcn_exp2f(mst[r] - mn[r]);
                lst[r] = lst[r] * f + rs[r];
                mst[r] = mn[r];
                #pragma unroll
                for (int nd = 0; nd < 4; ++nd) xacc[nd][r] *= f;
            }
        } else {
            #pragma unroll
            for (int r = 0; r < 4; ++r) lst[r] += rs[r];
        }

        // P -> LDS (bf16); same-wave write->read, lgkmcnt-ordered
        #pragma unroll
        for (int nj = 0; nj < 4; ++nj)
            #pragma unroll
            for (int r = 0; r < 4; ++r)
                Ps[w * 16 + lg * 4 + r][nj * 16 + lr] = bfround(sc[nj][r]);

        // X += P V
        bf16x8 pf0 = *(const bf16x8*)(&Ps[w * 16 + lr][lg * 8]);
        bf16x8 pf1 = *(const bf16x8*)(&Ps[w * 16 + lr][32 + lg * 8]);
        #pragma unroll
        for (int nd = 0; nd < 4; ++nd) {
            bf16x8 v0 = *(const bf16x8*)(&Vs[nd * 16 + lr][lg * 8]);
            bf16x8 v1 = *(const bf16x8*)(&Vs[nd * 16 + lr][32 + lg * 8]);
            xacc[nd] = __builtin_amdgcn_mfma_f32_16x16x32_bf16(pf0, v0, xacc[nd], 0, 0, 0);
            xacc[nd] = __builtin_amdgcn_mfma_f32_16x16x32_bf16(pf1, v1, xacc[nd], 0, 0, 0);
        }
    }

    // epilogue: X[b][q][h*64+dk] = xacc / l
    #pragma unroll
    for (int r = 0; r < 4; ++r) {
        const float l = lst[r];
        const float inv = l > 0.f ? 1.f / l : 0.f;
        const int q = qrow + lg * 4 + r;
        #pragma unroll
        for (int nd = 0; nd < 4; ++nd)
            Xb[(size_t)(b * NS + q) * ND + h * 64 + nd * 16 + lr] =
                bfround(xacc[nd][r] * inv);
    }
}

// ---------------------------------------------------------------------------
// Host launcher. Workspace (bf16 elements): wt(4*512*512), Qb, Kb, Vb, Vt, Xb.
// ---------------------------------------------------------------------------
extern "C" void kernel_launch(void* const* d_in, const int* in_sizes, int n_in,
                              void* d_out, int out_size, void* d_ws, size_t ws_size,
                              hipStream_t stream) {
    const float* query = (const float*)d_in[0];
    const float* key   = (const float*)d_in[1];
    const float* value = (const float*)d_in[2];
    const int*   mask  = (const int*)d_in[3];
    const float* Wq = (const float*)d_in[4];
    const float* bq = (const float*)d_in[5];
    const float* Wk = (const float*)d_in[6];
    const float* bk = (const float*)d_in[7];
    const float* Wv = (const float*)d_in[8];
    const float* bv = (const float*)d_in[9];
    const float* Wo = (const float*)d_in[10];
    const float* bo = (const float*)d_in[11];

    const size_t HEADSZ = (size_t)NB * NH * NS * NDK;  // 4194304
    unsigned short* wt = (unsigned short*)d_ws;
    unsigned short* Qb = wt + (size_t)4 * ND * ND;
    unsigned short* Kb = Qb + HEADSZ;
    unsigned short* Vb = Kb + HEADSZ;
    unsigned short* Vt = Vb + HEADSZ;
    unsigned short* Xb = Vt + HEADSZ;

    // 1. weights -> bf16, transposed
    wt_kernel<<<dim3(8, 8, 4), 256, 0, stream>>>(Wq, Wk, Wv, Wo, wt);

    // 2. QKV projections (one launch, z = q/k/v); Q pre-scaled by QSCALE
    gemm_kernel<true, false><<<768, 256, 0, stream>>>(
        query, key, value, wt, ND * ND, bq, bk, bv, (void*)Qb, HEADSZ * 2);

    // 3. V -> V^T per head
    vt_kernel<<<dim3(16, NB * NH), 256, 0, stream>>>(Vb, Vt);

    // 4. attention
    attn_kernel<<<1024, 256, 0, stream>>>(Qb, Kb, Vt, mask, Xb);

    // 5. output projection (fp32 out)
    gemm_kernel<false, true><<<256, 256, 0, stream>>>(
        Xb, Xb, Xb, wt + (size_t)3 * ND * ND, 0, bo, bo, bo, d_out, 0);
}

// Round 3
// 116.416 us; speedup vs baseline: 1.1725x; 1.0173x over previous
//
#include <hip/hip_runtime.h>
#include <hip/hip_bf16.h>

// Shapes (fixed by the reference)
#define NB 8
#define NS 1024
#define ND 512
#define NH 8
#define NDK 64

typedef __attribute__((ext_vector_type(8))) short bf16x8;
typedef __attribute__((ext_vector_type(4))) short s16x4;
typedef __attribute__((ext_vector_type(4))) float f32x4;
typedef __attribute__((ext_vector_type(16))) float f32x16;

// scores are computed in exp2 domain: Q is pre-scaled by 0.125 * log2(e)
#define QSCALE 0.18033688011112042f
#define NEGBIG -3.0e38f

#define CVTPK(dst, a, b) \
    asm("v_cvt_pk_bf16_f32 %0, %1, %2" : "=v"(dst) : "v"(a), "v"(b))
#define PLSWAP(a, b) \
    asm("v_permlane32_swap_b32 %0, %1" : "+v"(a), "+v"(b))

__device__ __forceinline__ unsigned short bfround(float f) {
    union { float f; unsigned u; } v; v.f = f;
    unsigned u = v.u;
    u += 0x7fffu + ((u >> 16) & 1u);
    return (unsigned short)(u >> 16);
}

// ---------------------------------------------------------------------------
// Kernel 1: transpose + convert the four 512x512 fp32 weights ([in][out]) into
// bf16 Wt[out][in] so the GEMM B-operand (k-contiguous per lane) reads linearly.
// ---------------------------------------------------------------------------
__global__ __launch_bounds__(256) void wt_kernel(const float* __restrict__ W0,
                                                 const float* __restrict__ W1,
                                                 const float* __restrict__ W2,
                                                 const float* __restrict__ W3,
                                                 unsigned short* __restrict__ wt) {
    __shared__ float sh[64][65];
    const int z = blockIdx.z;
    const float* W = z == 0 ? W0 : z == 1 ? W1 : z == 2 ? W2 : W3;
    unsigned short* out = wt + (size_t)z * ND * ND;
    const int o0 = blockIdx.x * 64, i0 = blockIdx.y * 64;
    const int tx = threadIdx.x & 63;
    const int ty = threadIdx.x >> 6;  // 0..3
    #pragma unroll
    for (int rr = 0; rr < 16; ++rr) {
        const int row = ty * 16 + rr;  // local i
        sh[row][tx] = W[(size_t)(i0 + row) * ND + o0 + tx];
    }
    __syncthreads();
    #pragma unroll
    for (int rr = 0; rr < 16; ++rr) {
        const int row = ty * 16 + rr;  // local o
        out[(size_t)(o0 + row) * ND + i0 + tx] = bfround(sh[tx][row]);
    }
}

// ---------------------------------------------------------------------------
// Kernel 2/5: GEMM  out = A(8192x512) @ W(512x512) + bias  (unchanged, passing)
// ---------------------------------------------------------------------------
template <bool A_F32, bool OUT_F32>
__global__ __launch_bounds__(256) void gemm_kernel(
    const void* __restrict__ A0, const void* __restrict__ A1, const void* __restrict__ A2,
    const unsigned short* __restrict__ wt_base, int wt_stride,
    const float* __restrict__ b0, const float* __restrict__ b1, const float* __restrict__ b2,
    void* __restrict__ out_base, size_t out_stride_bytes) {
    __shared__ unsigned short As[128][40];
    __shared__ unsigned short Bs[128][40];
    const int t = threadIdx.x;
    const int lane = t & 63, w = t >> 6;
    const int wr = w >> 1, wc = w & 1;
    const int lr = lane & 15, lg = lane >> 4;
    const int bid = blockIdx.x;
    const int u = (bid & 7) * (gridDim.x >> 3) + (bid >> 3);
    const int xt = u & 3, yt = (u >> 2) & 63, z = u >> 8;
    const void* Ap = z == 0 ? A0 : z == 1 ? A1 : A2;
    const float* bias = z == 0 ? b0 : z == 1 ? b1 : b2;
    const unsigned short* Wt = wt_base + (size_t)z * wt_stride;
    void* outp = (void*)((char*)out_base + (size_t)z * out_stride_bytes);
    const int m0 = yt * 128, n0 = xt * 128;

    f32x4 acc[4][4];
    #pragma unroll
    for (int i = 0; i < 4; ++i)
        #pragma unroll
        for (int j = 0; j < 4; ++j) acc[i][j] = (f32x4){0.f, 0.f, 0.f, 0.f};

    for (int kt = 0; kt < 16; ++kt) {
        const int k0 = kt * 32;
        __syncthreads();
        if (A_F32) {
            const float* A = (const float*)Ap;
            const int mrow = t >> 3, k4 = (t & 7) * 4;
            #pragma unroll
            for (int r = 0; r < 4; ++r) {
                const int m = mrow + 32 * r;
                float4 v = *(const float4*)(A + (size_t)(m0 + m) * ND + k0 + k4);
                unsigned p0, p1;
                CVTPK(p0, v.x, v.y);
                CVTPK(p1, v.z, v.w);
                uint2 pv; pv.x = p0; pv.y = p1;
                *(uint2*)(&As[m][k4]) = pv;
            }
        } else {
            const unsigned short* A = (const unsigned short*)Ap;
            #pragma unroll
            for (int r = 0; r < 2; ++r) {
                const int idx = t + 256 * r;
                const int m = idx >> 2, k8 = (idx & 3) * 8;
                *(bf16x8*)(&As[m][k8]) =
                    *(const bf16x8*)(A + (size_t)(m0 + m) * ND + k0 + k8);
            }
        }
        #pragma unroll
        for (int r = 0; r < 2; ++r) {
            const int idx = t + 256 * r;
            const int n = idx >> 2, k8 = (idx & 3) * 8;
            *(bf16x8*)(&Bs[n][k8]) =
                *(const bf16x8*)(Wt + (size_t)(n0 + n) * ND + k0 + k8);
        }
        __syncthreads();
        bf16x8 af[4], bfv[4];
        #pragma unroll
        for (int mi = 0; mi < 4; ++mi)
            af[mi] = *(const bf16x8*)(&As[wr * 64 + mi * 16 + lr][lg * 8]);
        #pragma unroll
        for (int nj = 0; nj < 4; ++nj)
            bfv[nj] = *(const bf16x8*)(&Bs[wc * 64 + nj * 16 + lr][lg * 8]);
        #pragma unroll
        for (int mi = 0; mi < 4; ++mi)
            #pragma unroll
            for (int nj = 0; nj < 4; ++nj)
                acc[mi][nj] = __builtin_amdgcn_mfma_f32_16x16x32_bf16(
                    af[mi], bfv[nj], acc[mi][nj], 0, 0, 0);
    }

    const float osc = (!OUT_F32 && z == 0) ? QSCALE : 1.0f;
    #pragma unroll
    for (int mi = 0; mi < 4; ++mi) {
        #pragma unroll
        for (int nj = 0; nj < 4; ++nj) {
            const int n = n0 + wc * 64 + nj * 16 + lr;
            const float bv = bias[n];
            #pragma unroll
            for (int r = 0; r < 4; ++r) {
                const int m = m0 + wr * 64 + mi * 16 + lg * 4 + r;
                const float val = (acc[mi][nj][r] + bv) * osc;
                if (OUT_F32) {
                    ((float*)outp)[(size_t)m * ND + n] = val;
                } else {
                    const int bb = m >> 10, s = m & 1023;    // m = b*S + s
                    const int hh = n >> 6, dk = n & 63;      // n = h*64 + dk
                    ((unsigned short*)outp)[(((size_t)(bb * NH + hh) * NS + s) << 6) + dk] =
                        bfround(val);
                }
            }
        }
    }
}

// ---------------------------------------------------------------------------
// Kernel 3: per-(b,h) transpose V (S,DK) -> Vt (DK,S). (unchanged, passing)
// ---------------------------------------------------------------------------
__global__ __launch_bounds__(256) void vt_kernel(const unsigned short* __restrict__ Vb,
                                                 unsigned short* __restrict__ Vt) {
    __shared__ unsigned short Ts[64][72];
    const int t = threadIdx.x;
    const int bh = blockIdx.y;
    const int s0 = blockIdx.x * 64;
    const unsigned short* Vh = Vb + (size_t)bh * NS * NDK;
    unsigned short* Vth = Vt + (size_t)bh * NDK * NS;
    #pragma unroll
    for (int r = 0; r < 2; ++r) {
        const int idx = t + 256 * r;
        const int sl = idx >> 3, d8 = (idx & 7) * 8;
        *(bf16x8*)(&Ts[sl][d8]) = *(const bf16x8*)(Vh + (size_t)(s0 + sl) * NDK + d8);
    }
    __syncthreads();
    #pragma unroll
    for (int r = 0; r < 2; ++r) {
        const int idx = t + 256 * r;
        const int dl = idx >> 3, s8 = (idx & 7) * 8;
        unsigned short tmp[8];
        #pragma unroll
        for (int e = 0; e < 8; ++e) tmp[e] = Ts[s8 + e][dl];
        *(bf16x8*)(Vth + (size_t)dl * NS + s0 + s8) = *(bf16x8*)tmp;
    }
}

// ---------------------------------------------------------------------------
// Kernel 4: flash attention, swapped-operand 32x32 MFMA, in-register softmax.
// 4 waves/block, each wave owns 32 q rows; KV tile = 64 per iter (2 32x32
// S-tiles). No barriers; no K/V/P LDS. K and V^T fragments load directly from
// global (L2-resident, XCD swizzle keeps a head's q-blocks on one XCD).
//
// QK^T swapped: S^T = mfma32(K, Q): lane holds col q=lane&31, rows
// kv = (reg&3)+8*(reg>>2)+4*hi per tile -> row max/sum is an in-register tree
// + one shfl_xor(32). P stays in registers: cvt_pk pairs + permlane32_swap
// produce PV B-frags (T12; swap(word[m],word[m+1]) -> frag regs {0,2},{1,3}).
// PV swapped: O^T = mfma32(V^T, P). Mask = additive bias via tiny per-wave LDS.
// ---------------------------------------------------------------------------
__global__ __launch_bounds__(256, 2) void attn_kernel(const unsigned short* __restrict__ Qb,
                                                      const unsigned short* __restrict__ Kb,
                                                      const unsigned short* __restrict__ Vt,
                                                      const int* __restrict__ mask,
                                                      unsigned short* __restrict__ Xb) {
    __shared__ float bias_lds[4][64];
    const int t = threadIdx.x;
    const int lane = t & 63, w = t >> 6;
    const int q32 = lane & 31, hi = lane >> 5;
    // XCD swizzle: 8 q-tiles of one head contiguous on one XCD
    const int bid = blockIdx.x;                  // 512 blocks
    const int u = (bid & 7) * 64 + (bid >> 3);
    const int bh = u >> 3, xq = u & 7;
    const int b = bh >> 3, h = bh & 7;
    const int q = xq * 128 + w * 32 + q32;
    const unsigned short* Qh = Qb + (size_t)bh * NS * NDK;
    const unsigned short* Kh = Kb + (size_t)bh * NS * NDK;
    const unsigned short* Vh = Vt + (size_t)bh * NDK * NS;
    const int* mk = mask + b * NS;

    // Q fragments (B-operand: col=q, k=dk): 4 chunks of K=16
    const unsigned short* Qp = Qh + (size_t)q * NDK + hi * 8;
    bf16x8 qf0 = *(const bf16x8*)(Qp + 0);
    bf16x8 qf1 = *(const bf16x8*)(Qp + 16);
    bf16x8 qf2 = *(const bf16x8*)(Qp + 32);
    bf16x8 qf3 = *(const bf16x8*)(Qp + 48);

    f32x16 acc0 = {}, acc1 = {};   // O^T tiles: dk 0-31, 32-63 (col = q)
    float m_st = -1.0e30f, l_st = 0.f;

    for (int it = 0; it < 16; ++it) {
        const int kv0 = it * 64;
        // mask bias -> per-wave LDS (write->read same wave, lgkmcnt-ordered)
        bias_lds[w][lane] = mk[kv0 + lane] ? 0.f : NEGBIG;

        // K fragments (A-operand: row=kv, k=dk), 2 tiles x 4 chunks
        const unsigned short* Kp0 = Kh + (size_t)(kv0 + q32) * NDK + hi * 8;
        const unsigned short* Kp1 = Kp0 + 32 * NDK;
        bf16x8 kf00 = *(const bf16x8*)(Kp0 + 0);
        bf16x8 kf01 = *(const bf16x8*)(Kp0 + 16);
        bf16x8 kf02 = *(const bf16x8*)(Kp0 + 32);
        bf16x8 kf03 = *(const bf16x8*)(Kp0 + 48);
        bf16x8 kf10 = *(const bf16x8*)(Kp1 + 0);
        bf16x8 kf11 = *(const bf16x8*)(Kp1 + 16);
        bf16x8 kf12 = *(const bf16x8*)(Kp1 + 32);
        bf16x8 kf13 = *(const bf16x8*)(Kp1 + 48);
        // V^T fragments (A-operand: row=dk, k=kv) — issue early, consumed after
        // softmax so global latency hides under the VALU phase
        const unsigned short* Vp0 = Vh + (size_t)q32 * NS + kv0 + hi * 8;
        const unsigned short* Vp1 = Vp0 + 32 * NS;
        bf16x8 vf00 = *(const bf16x8*)(Vp0 + 0);
        bf16x8 vf01 = *(const bf16x8*)(Vp0 + 16);
        bf16x8 vf02 = *(const bf16x8*)(Vp0 + 32);
        bf16x8 vf03 = *(const bf16x8*)(Vp0 + 48);
        bf16x8 vf10 = *(const bf16x8*)(Vp1 + 0);
        bf16x8 vf11 = *(const bf16x8*)(Vp1 + 16);
        bf16x8 vf12 = *(const bf16x8*)(Vp1 + 32);
        bf16x8 vf13 = *(const bf16x8*)(Vp1 + 48);

        // S^T tiles
        f32x16 sc0 = {}, sc1 = {};
        sc0 = __builtin_amdgcn_mfma_f32_32x32x16_bf16(kf00, qf0, sc0, 0, 0, 0);
        sc0 = __builtin_amdgcn_mfma_f32_32x32x16_bf16(kf01, qf1, sc0, 0, 0, 0);
        sc0 = __builtin_amdgcn_mfma_f32_32x32x16_bf16(kf02, qf2, sc0, 0, 0, 0);
        sc0 = __builtin_amdgcn_mfma_f32_32x32x16_bf16(kf03, qf3, sc0, 0, 0, 0);
        sc1 = __builtin_amdgcn_mfma_f32_32x32x16_bf16(kf10, qf0, sc1, 0, 0, 0);
        sc1 = __builtin_amdgcn_mfma_f32_32x32x16_bf16(kf11, qf1, sc1, 0, 0, 0);
        sc1 = __builtin_amdgcn_mfma_f32_32x32x16_bf16(kf12, qf2, sc1, 0, 0, 0);
        sc1 = __builtin_amdgcn_mfma_f32_32x32x16_bf16(kf13, qf3, sc1, 0, 0, 0);

        // mask bias: rows of reg-group mm are 8*mm + 4*hi + {0..3}
        {
            const float* bl = &bias_lds[w][4 * hi];
            #pragma unroll
            for (int mm = 0; mm < 4; ++mm) {
                const f32x4 bv0 = *(const f32x4*)(bl + 8 * mm);
                const f32x4 bv1 = *(const f32x4*)(bl + 32 + 8 * mm);
                #pragma unroll
                for (int c = 0; c < 4; ++c) {
                    sc0[4 * mm + c] += bv0[c];
                    sc1[4 * mm + c] += bv1[c];
                }
            }
        }

        // row max (this lane holds 32 of the 64 kv entries; partner has rest)
        float tv[16];
        #pragma unroll
        for (int r = 0; r < 16; ++r) tv[r] = fmaxf(sc0[r], sc1[r]);
        #pragma unroll
        for (int s = 8; s > 0; s >>= 1)
            #pragma unroll
            for (int r = 0; r < 16; ++r)
                if (r < s) tv[r] = fmaxf(tv[r], tv[r + s]);
        float mx = fmaxf(tv[0], __shfl_xor(tv[0], 32));
        const float mn = fmaxf(m_st, mx);

        // exp2 + row sum
        #pragma unroll
        for (int r = 0; r < 16; ++r) {
            sc0[r] = __builtin_amdgcn_exp2f(sc0[r] - mn);
            sc1[r] = __builtin_amdgcn_exp2f(sc1[r] - mn);
        }
        #pragma unroll
        for (int r = 0; r < 16; ++r) tv[r] = sc0[r] + sc1[r];
        #pragma unroll
        for (int s = 8; s > 0; s >>= 1)
            #pragma unroll
            for (int r = 0; r < 16; ++r)
                if (r < s) tv[r] += tv[r + s];
        const float rs = tv[0] + __shfl_xor(tv[0], 32);

        const bool ch = mn > m_st;
        if (__any(ch)) {
            const float f = __builtin_amdgcn_exp2f(m_st - mn);
            l_st = l_st * f + rs;
            m_st = mn;
            #pragma unroll
            for (int r = 0; r < 16; ++r) { acc0[r] *= f; acc1[r] *= f; }
        } else {
            l_st += rs;
        }

        // P -> bf16 PV B-frags in-register: per tile, words w[m] cover rows
        // 8m+4hi+{0..3}; swap(w[m], w[m+1]) yields frag regs (lo->{0,1}, hi->{2,3})
        union U8 { unsigned u[4]; bf16x8 v; };
        bf16x8 pA0, pA1, pB0, pB1;
        {
            unsigned w00, w01, w10, w11, w20, w21, w30, w31;
            CVTPK(w00, sc0[0], sc0[1]);  CVTPK(w01, sc0[2], sc0[3]);
            CVTPK(w10, sc0[4], sc0[5]);  CVTPK(w11, sc0[6], sc0[7]);
            CVTPK(w20, sc0[8], sc0[9]);  CVTPK(w21, sc0[10], sc0[11]);
            CVTPK(w30, sc0[12], sc0[13]); CVTPK(w31, sc0[14], sc0[15]);
            PLSWAP(w00, w10); PLSWAP(w01, w11);
            PLSWAP(w20, w30); PLSWAP(w21, w31);
            U8 f0; f0.u[0] = w00; f0.u[1] = w01; f0.u[2] = w10; f0.u[3] = w11;
            U8 f1; f1.u[0] = w20; f1.u[1] = w21; f1.u[2] = w30; f1.u[3] = w31;
            pA0 = f0.v; pA1 = f1.v;
        }
        {
            unsigned w00, w01, w10, w11, w20, w21, w30, w31;
            CVTPK(w00, sc1[0], sc1[1]);  CVTPK(w01, sc1[2], sc1[3]);
            CVTPK(w10, sc1[4], sc1[5]);  CVTPK(w11, sc1[6], sc1[7]);
            CVTPK(w20, sc1[8], sc1[9]);  CVTPK(w21, sc1[10], sc1[11]);
            CVTPK(w30, sc1[12], sc1[13]); CVTPK(w31, sc1[14], sc1[15]);
            PLSWAP(w00, w10); PLSWAP(w01, w11);
            PLSWAP(w20, w30); PLSWAP(w21, w31);
            U8 f0; f0.u[0] = w00; f0.u[1] = w01; f0.u[2] = w10; f0.u[3] = w11;
            U8 f1; f1.u[0] = w20; f1.u[1] = w21; f1.u[2] = w30; f1.u[3] = w31;
            pB0 = f0.v; pB1 = f1.v;
        }

        // O^T += V^T P
        acc0 = __builtin_amdgcn_mfma_f32_32x32x16_bf16(vf00, pA0, acc0, 0, 0, 0);
        acc0 = __builtin_amdgcn_mfma_f32_32x32x16_bf16(vf01, pA1, acc0, 0, 0, 0);
        acc0 = __builtin_amdgcn_mfma_f32_32x32x16_bf16(vf02, pB0, acc0, 0, 0, 0);
        acc0 = __builtin_amdgcn_mfma_f32_32x32x16_bf16(vf03, pB1, acc0, 0, 0, 0);
        acc1 = __builtin_amdgcn_mfma_f32_32x32x16_bf16(vf10, pA0, acc1, 0, 0, 0);
        acc1 = __builtin_amdgcn_mfma_f32_32x32x16_bf16(vf11, pA1, acc1, 0, 0, 0);
        acc1 = __builtin_amdgcn_mfma_f32_32x32x16_bf16(vf12, pB0, acc1, 0, 0, 0);
        acc1 = __builtin_amdgcn_mfma_f32_32x32x16_bf16(vf13, pB1, acc1, 0, 0, 0);
    }

    // epilogue: X[b][q][h*64+dk] = O^T / l ; dk = od*32 + 8*mm + 4*hi + c
    const float inv = l_st > 0.f ? 1.f / l_st : 0.f;
    unsigned short* Xp = Xb + (size_t)(b * NS + q) * ND + h * 64 + 4 * hi;
    #pragma unroll
    for (int mm = 0; mm < 4; ++mm) {
        unsigned w0, w1;
        CVTPK(w0, acc0[4 * mm] * inv, acc0[4 * mm + 1] * inv);
        CVTPK(w1, acc0[4 * mm + 2] * inv, acc0[4 * mm + 3] * inv);
        uint2 pv; pv.x = w0; pv.y = w1;
        *(uint2*)(Xp + 8 * mm) = pv;
        CVTPK(w0, acc1[4 * mm] * inv, acc1[4 * mm + 1] * inv);
        CVTPK(w1, acc1[4 * mm + 2] * inv, acc1[4 * mm + 3] * inv);
        pv.x = w0; pv.y = w1;
        *(uint2*)(Xp + 32 + 8 * mm) = pv;
    }
}

// ---------------------------------------------------------------------------
// Host launcher. Workspace (bf16 elements): wt(4*512*512), Qb, Kb, Vb, Vt, Xb.
// ---------------------------------------------------------------------------
extern "C" void kernel_launch(void* const* d_in, const int* in_sizes, int n_in,
                              void* d_out, int out_size, void* d_ws, size_t ws_size,
                              hipStream_t stream) {
    const float* query = (const float*)d_in[0];
    const float* key   = (const float*)d_in[1];
    const float* value = (const float*)d_in[2];
    const int*   mask  = (const int*)d_in[3];
    const float* Wq = (const float*)d_in[4];
    const float* bq = (const float*)d_in[5];
    const float* Wk = (const float*)d_in[6];
    const float* bk = (const float*)d_in[7];
    const float* Wv = (const float*)d_in[8];
    const float* bv = (const float*)d_in[9];
    const float* Wo = (const float*)d_in[10];
    const float* bo = (const float*)d_in[11];

    const size_t HEADSZ = (size_t)NB * NH * NS * NDK;  // 4194304
    unsigned short* wt = (unsigned short*)d_ws;
    unsigned short* Qb = wt + (size_t)4 * ND * ND;
    unsigned short* Kb = Qb + HEADSZ;
    unsigned short* Vb = Kb + HEADSZ;
    unsigned short* Vt = Vb + HEADSZ;
    unsigned short* Xb = Vt + HEADSZ;

    // 1. weights -> bf16, transposed
    wt_kernel<<<dim3(8, 8, 4), 256, 0, stream>>>(Wq, Wk, Wv, Wo, wt);

    // 2. QKV projections (one launch, z = q/k/v); Q pre-scaled by QSCALE
    gemm_kernel<true, false><<<768, 256, 0, stream>>>(
        query, key, value, wt, ND * ND, bq, bk, bv, (void*)Qb, HEADSZ * 2);

    // 3. V -> V^T per head
    vt_kernel<<<dim3(16, NB * NH), 256, 0, stream>>>(Vb, Vt);

    // 4. attention (512 blocks, 4 waves each, no barriers)
    attn_kernel<<<512, 256, 0, stream>>>(Qb, Kb, Vt, mask, Xb);

    // 5. output projection (fp32 out)
    gemm_kernel<false, true><<<256, 256, 0, stream>>>(
        Xb, Xb, Xb, wt + (size_t)3 * ND * ND, 0, bo, bo, bo, d_out, 0);
}